// Round 15
// baseline (41.817 us; speedup 1.0000x reference)
//
#include <hip/hip_runtime.h>
#include <math.h>

#define NROWS 4096
#define D 128
#define SPC 8
#define KRET 7
#define MARGIN 0.2f
#define NTILE 32              // 4096/128 col-tiles
#define CPT 14                // candidates per (row, 128-col tile): 2 halves x 7
#define CPR (NTILE * CPT)     // 448 candidates per row

typedef unsigned long long u64;
typedef unsigned int u32;
typedef __attribute__((ext_vector_type(8))) short short8;    // 8 bf16 (4 VGPRs)
typedef __attribute__((ext_vector_type(16))) float f32x16;   // 32x32 MFMA accumulator

__device__ __forceinline__ u32 minu32(u32 a, u32 b) { return a < b ? a : b; }
__device__ __forceinline__ u32 maxu32(u32 a, u32 b) { return a > b ? a : b; }

// bf16 round-to-nearest-even
__device__ __forceinline__ ushort f2bf_rne(float x) {
    unsigned u = __float_as_uint(x);
    return (ushort)((u + 0x7fffu + ((u >> 16) & 1u)) >> 16);
}
__device__ __forceinline__ u32 pack2bf(float lo, float hi) {
    return (u32)f2bf_rne(lo) | ((u32)f2bf_rne(hi) << 16);
}

// guarded sorted-7 single insert (14 ops)
__device__ __forceinline__ void ins7(u32 (&s)[KRET], u32 pk) {
#pragma unroll
    for (int k = 0; k < KRET; ++k) {
        const u32 lo = minu32(s[k], pk);
        pk = maxu32(s[k], pk);
        s[k] = lo;
    }
}

// dual insert of sorted pair (q0<=q1) into sorted-7 (r8/r12-validated; uses old s)
__device__ __forceinline__ void ins7x2(u32 (&s)[KRET], u32 q0, u32 q1) {
    s[6] = minu32(s[6], minu32(maxu32(s[5], q0), maxu32(s[4], q1)));
    s[5] = minu32(s[5], minu32(maxu32(s[4], q0), maxu32(s[3], q1)));
    s[4] = minu32(s[4], minu32(maxu32(s[3], q0), maxu32(s[2], q1)));
    s[3] = minu32(s[3], minu32(maxu32(s[2], q0), maxu32(s[1], q1)));
    s[2] = minu32(s[2], minu32(maxu32(s[1], q0), maxu32(s[0], q1)));
    s[1] = minu32(s[1], minu32(maxu32(s[0], q0), q1));
    s[0] = minu32(s[0], q0);
}

// Fragment-order bf16 layout (both matrices):
//   chunk(g, kkg, hi) = ((g*8 + kkg)*2 + hi) * 256 u16  (512 B); lane slot il*8 u16.
// -> wave frag read is a contiguous 1024 B global load (coalesced, L2-hot).
//
// ws layout (floats) — non-overlapping:
//   [4096 .. 8191]        diag
//   [8192 .. 40959]       posd (4096 x 8 f32, clamped d^2)
//   [65536 .. 327679]     embF  (fragment-order bf16, 1 MB)
//   [327680 .. 589823]    emb1F (fragment-order bf16, 1 MB)
//   [589824 .. 2424831]   cand (u32, 4096 x 448)
//   [2424832 .. 2428927]  rowls
//   [2428928 .. 2433023]  rowcnt
// Fallback path: [0],[1] accum, [2..2+NROWS) diag.

// ---- prep: f32 -> fragment-order bf16 + exact f32 Gram diagonal ----
__global__ __launch_bounds__(256) void prep_kernel(const float* __restrict__ emb,
                                                   const float* __restrict__ emb1,
                                                   ushort* __restrict__ embF,
                                                   ushort* __restrict__ emb1F,
                                                   float* __restrict__ diag) {
    __shared__ float pls[4][32];
    const int t = threadIdx.x;
    const int wv = t >> 6, l = t & 63;
    const int il = l & 31, hi = l >> 5;
    const int g = blockIdx.x;            // row-group 0..127
    const int row = g * 32 + il;
    const float* pa = emb  + (size_t)row * D;
    const float* pb = emb1 + (size_t)row * D;
    float dacc = 0.f;
#pragma unroll
    for (int kp = 0; kp < 2; ++kp) {
        const int kkg = wv * 2 + kp;
        const int k0 = kkg * 16 + hi * 8;
        const float4 a0 = *(const float4*)(pa + k0);
        const float4 a1 = *(const float4*)(pa + k0 + 4);
        const float4 b0 = *(const float4*)(pb + k0);
        const float4 b1 = *(const float4*)(pb + k0 + 4);
        dacc += a0.x * b0.x + a0.y * b0.y + a0.z * b0.z + a0.w * b0.w;
        dacc += a1.x * b1.x + a1.y * b1.y + a1.z * b1.z + a1.w * b1.w;
        uint4 ua, ub;
        ua.x = pack2bf(a0.x, a0.y); ua.y = pack2bf(a0.z, a0.w);
        ua.z = pack2bf(a1.x, a1.y); ua.w = pack2bf(a1.z, a1.w);
        ub.x = pack2bf(b0.x, b0.y); ub.y = pack2bf(b0.z, b0.w);
        ub.z = pack2bf(b1.x, b1.y); ub.w = pack2bf(b1.z, b1.w);
        const size_t dst = ((size_t)(g * 8 + kkg) * 2 + hi) * 256 + il * 8;  // u16 units
        *(uint4*)(embF + dst)  = ua;
        *(uint4*)(emb1F + dst) = ub;
    }
    dacc += __shfl_xor(dacc, 32, 64);    // combine k-halves (hi 0/1)
    if (hi == 0) pls[wv][il] = dacc;
    __syncthreads();
    if (t < 32) diag[g * 32 + t] = (pls[0][t] + pls[1][t]) + (pls[2][t] + pls[3][t]);
}

// ---- dist: 64x128 tile, 4 waves = (row-half, col-half), each 32i x 64j ----
// Grid 2048 blocks -> 6 blocks/CU (launch_bounds(256,6)): ~24 waves/CU vs 16 before.
// Same swapped-operand 32x32x16 MFMA, same kkg order (bit-identical accumulators),
// register-resident selection, tile-interleaved (epilogue overlaps next tile's MFMAs).
__global__ __launch_bounds__(256, 6) void dist_mfma(const ushort* __restrict__ embF,
                                                    const ushort* __restrict__ emb1F,
                                                    const int* __restrict__ labels,
                                                    const int* __restrict__ labels1,
                                                    const float* __restrict__ diag,
                                                    float* __restrict__ posd, u32* __restrict__ cand) {
    __shared__ float sdA[64], sdB[128];
    __shared__ int sLi[64], sLj[128];
    __shared__ int s_lmin[4], s_lmax[4];

    const int t = threadIdx.x;
    const int i0 = blockIdx.y * 64, j0 = blockIdx.x * 128;
    const int w = t >> 6, l = t & 63;

    {   // diag + labels -> LDS + per-wave label min/max (wave0/3: A rows, wave1/2: B cols)
        int lab;
        if (t < 64)       { sdA[t] = diag[i0 + t]; lab = labels1[i0 + t]; sLi[t] = lab; }
        else if (t < 192) { sdB[t - 64] = diag[j0 + t - 64]; lab = labels[j0 + t - 64]; sLj[t - 64] = lab; }
        else              { lab = labels1[i0 + (t & 63)]; }   // duplicate A labels
        int mn = lab, mx = lab;
#pragma unroll
        for (int off = 1; off < 64; off <<= 1) {
            mn = min(mn, __shfl_xor(mn, off, 64));
            mx = max(mx, __shfl_xor(mx, off, 64));
        }
        if (l == 0) { s_lmin[w] = mn; s_lmax[w] = mx; }
    }

    const int il = l & 31;            // lane's i within wave (C/D col)
    const int hi = l >> 5;            // j-half select (C/D row +4*hi)
    const int rh = w >> 1, jh = w & 1;
    const int irow = rh * 32 + il;    // block-local anchor row
    const int laneoff = hi * 256 + il * 8;   // u16: contiguous 1024B per wave instr
    const ushort* Ab = embF  + ((size_t)(blockIdx.y * 2 + rh) * 8) * 512 + laneoff;
    const ushort* Bb = emb1F + ((size_t)(blockIdx.x * 4 + jh * 2) * 8) * 512 + laneoff;

    // cache the anchor-row frags (loads issue before the barrier)
    short8 bfr[8];
#pragma unroll
    for (int kkg = 0; kkg < 8; ++kkg)
        bfr[kkg] = *(const short8*)(Ab + (size_t)kkg * 512);

    __syncthreads();          // the ONLY barrier

    const bool hasPos = !((max(s_lmax[0], s_lmax[3]) < min(s_lmin[1], s_lmin[2])) ||
                          (max(s_lmax[1], s_lmax[2]) < min(s_lmin[0], s_lmin[3])));
    const float di = sdA[irow];
    const int gi = i0 + irow;
    const int li = hasPos ? sLi[irow] : 0;

    u32 s[KRET];
#pragma unroll
    for (int k = 0; k < KRET; ++k) s[k] = 0xFFFFFFFFu;

#pragma unroll
    for (int n = 0; n < 2; ++n) {
        f32x16 acc;
#pragma unroll
        for (int r = 0; r < 16; ++r) acc[r] = 0.f;
#pragma unroll
        for (int kkg = 0; kkg < 8; ++kkg) {
            const short8 afr = *(const short8*)(Bb + (size_t)(n * 8 + kkg) * 512);
            acc = __builtin_amdgcn_mfma_f32_32x32x16_bf16(afr, bfr[kkg], acc, 0, 0, 0);
        }

        // epilogue tile n: j_block = jh*64 + n*32 + 8g + 4*hi + q  (g = reg>>2, q = reg&3)
#pragma unroll
        for (int g = 0; g < 4; ++g) {
            const int jb = jh * 64 + n * 32 + 8 * g + 4 * hi;
            const float4 dj4 = *(const float4*)(sdB + jb);
            const float djv[4] = {dj4.x, dj4.y, dj4.z, dj4.w};
            u32 pk[4];
            if (!hasPos) {
#pragma unroll
                for (int q = 0; q < 4; ++q) {
                    const int r = g * 4 + q;
                    const float d2c = fmaxf(fmaf(-2.f, acc[r], di + djv[q]), 1e-4f);
                    pk[q] = (__float_as_uint(d2c) & 0xFFFF0000u) | (u32)(j0 + jb + q);
                }
            } else {
                const int4 lj4 = *(const int4*)(sLj + jb);
                const int ljv[4] = {lj4.x, lj4.y, lj4.z, lj4.w};
#pragma unroll
                for (int q = 0; q < 4; ++q) {
                    const int r = g * 4 + q;
                    const int gj = j0 + jb + q;
                    const float d2c = fmaxf(fmaf(-2.f, acc[r], di + djv[q]), 1e-4f);
                    const bool pos = (ljv[q] == li) && (gi != gj);
                    if (pos) posd[(size_t)gi * SPC + (gj & (SPC - 1))] = d2c;
                    pk[q] = (pos ? 0xFFFF0000u : (__float_as_uint(d2c) & 0xFFFF0000u)) | (u32)gj;
                }
            }
            {
                const u32 q0 = minu32(pk[0], pk[1]), q1 = maxu32(pk[0], pk[1]);
                if (q0 < s[KRET - 1]) ins7x2(s, q0, q1);
            }
            {
                const u32 q0 = minu32(pk[2], pk[3]), q1 = maxu32(pk[2], pk[3]);
                if (q0 < s[KRET - 1]) ins7x2(s, q0, q1);
            }
        }
    }

    // merge the two lane-halves of each row (exchange originals first, then insert)
    u32 o[KRET];
#pragma unroll
    for (int k = 0; k < KRET; ++k) o[k] = (u32)__shfl_xor((int)s[k], 32, 64);
#pragma unroll
    for (int k = 0; k < KRET; ++k) if (o[k] < s[KRET - 1]) ins7(s, o[k]);

    if (hi == 0) {
        u32* cw = cand + (size_t)gi * CPR + (j0 >> 7) * CPT + jh * KRET;
#pragma unroll
        for (int k = 0; k < KRET; ++k) cw[k] = s[k];
    }
}

// ---- merge 448 u32 candidates/row -> global top-7, validity, loss. Wave per row. ----
__global__ __launch_bounds__(256) void merge_kernel(const float* __restrict__ emb,
                                                    const float* __restrict__ posd,
                                                    const u32* __restrict__ cand,
                                                    float* __restrict__ rowls,
                                                    float* __restrict__ rowcnt) {
    const int lane = threadIdx.x & 63;
    const int i = blockIdx.x * 4 + (threadIdx.x >> 6);
    const u32* cr = cand + (size_t)i * CPR;
    u32 e[7];
#pragma unroll
    for (int q = 0; q < 7; ++q) e[q] = cr[q * 64 + lane];

    u32 w[KRET];
#pragma unroll
    for (int r = 0; r < KRET; ++r) {
        u32 m = e[0];
#pragma unroll
        for (int q = 1; q < 7; ++q) m = minu32(m, e[q]);
#pragma unroll
        for (int off = 1; off < 64; off <<= 1) m = minu32(m, (u32)__shfl_xor((int)m, off, 64));
        w[r] = m;
#pragma unroll
        for (int q = 0; q < 7; ++q) e[q] = (e[q] == m) ? 0xFFFFFFFFu : e[q];
    }

    // sort winners by column index: rotate to (col12 << 20 | score16 << 4), Batcher-8
    u32 s[8];
#pragma unroll
    for (int r = 0; r < KRET; ++r) s[r] = (w[r] << 20) | (w[r] >> 12);
    s[7] = 0xFFFFFFFFu;
#define CE(x, y) { u32 lo = minu32(s[x], s[y]); u32 hi2 = maxu32(s[x], s[y]); s[x] = lo; s[y] = hi2; }
    CE(0,1) CE(2,3) CE(4,5) CE(6,7)
    CE(0,2) CE(1,3) CE(4,6) CE(5,7)
    CE(1,2) CE(5,6)
    CE(0,4) CE(1,5) CE(2,6) CE(3,7)
    CE(2,4) CE(3,5)
    CE(1,2) CE(3,4) CE(5,6)
#undef CE

    const int ig = i & (SPC - 1);
    float ls = 0.f, cnt = 0.f;
    bool any = false;
    bool v[KRET];
    int nidx[KRET];
#pragma unroll
    for (int k = 0; k < KRET; ++k) {
        nidx[k] = (int)(s[k] >> 20);
        const float d2n = __uint_as_float(((s[k] >> 4) & 0xFFFF0u) << 12);  // score16 << 16
        const float dneg = sqrtf(d2n);
        const int m = k + (k >= ig ? 1 : 0);
        const float dp = sqrtf(posd[(size_t)i * SPC + m]);
        v[k] = dp < dneg + MARGIN;       // wave-uniform
        any = any || v[k];
    }

    if (any) {
        const float a0 = emb[(size_t)i * D + lane];
        const float a1 = emb[(size_t)i * D + 64 + lane];
#pragma unroll
        for (int k = 0; k < KRET; ++k) {
            if (v[k]) {
                const int m = k + (k >= ig ? 1 : 0);
                const int tp = (i & ~(SPC - 1)) + m;
                const int tn = nidx[k];
                float d0 = emb[(size_t)tp * D + lane] - a0;
                float d1 = emb[(size_t)tp * D + 64 + lane] - a1;
                float sp = d0 * d0 + d1 * d1;
                float g0 = emb[(size_t)tn * D + lane] - a0;
                float g1 = emb[(size_t)tn * D + 64 + lane] - a1;
                float sn = g0 * g0 + g1 * g1;
#pragma unroll
                for (int off = 1; off < 64; off <<= 1) {
                    sp += __shfl_xor(sp, off, 64);
                    sn += __shfl_xor(sn, off, 64);
                }
                ls += (sqrtf(sp + 1e-8f) + MARGIN) + fmaxf(MARGIN - sqrtf(sn + 1e-8f), 0.f);
                cnt += 1.f;
            }
        }
    }
    if (lane == 0) {           // always write: poison-safe, deterministic
        rowls[i] = ls;
        rowcnt[i] = cnt;
    }
}

// ---- deterministic single-block reduction over 4096 per-row partials ----
__global__ __launch_bounds__(256) void finalize_kernel(const float* __restrict__ rowls,
                                                       const float* __restrict__ rowcnt,
                                                       float* __restrict__ out) {
    const int t = threadIdx.x;
    __shared__ float sls[4], scnt[4];
    float ls = 0.f, cnt = 0.f;
#pragma unroll
    for (int q = 0; q < NROWS / 256; ++q) {
        ls += rowls[q * 256 + t];
        cnt += rowcnt[q * 256 + t];
    }
#pragma unroll
    for (int off = 1; off < 64; off <<= 1) {
        ls += __shfl_xor(ls, off, 64);
        cnt += __shfl_xor(cnt, off, 64);
    }
    if ((t & 63) == 0) { sls[t >> 6] = ls; scnt[t >> 6] = cnt; }
    __syncthreads();
    if (t == 0) {
        float L = sls[0] + sls[1] + sls[2] + sls[3];
        float C = scnt[0] + scnt[1] + scnt[2] + scnt[3];
        out[0] = C > 0.f ? L / C : L;
    }
}

// ---------------- Fallback path (round-1, only if ws too small) ----------------
__global__ __launch_bounds__(256) void diag_kernel(const float* __restrict__ emb,
                                                   const float* __restrict__ emb1,
                                                   float* __restrict__ diag) {
    int wave = threadIdx.x >> 6;
    int lane = threadIdx.x & 63;
    int row = blockIdx.x * 4 + wave;
    const float* a = emb + (size_t)row * D;
    const float* b = emb1 + (size_t)row * D;
    float s = a[lane] * b[lane] + a[lane + 64] * b[lane + 64];
    for (int off = 32; off > 0; off >>= 1) s += __shfl_down(s, off, 64);
    if (lane == 0) diag[row] = s;
}

__global__ __launch_bounds__(256) void main_kernel(const float* __restrict__ emb,
                                                   const float* __restrict__ emb1,
                                                   const int* __restrict__ labels,
                                                   const int* __restrict__ labels1,
                                                   const float* __restrict__ diag,
                                                   float* __restrict__ ws_acc) {
    const int i = blockIdx.x;
    const int tid = threadIdx.x;
    __shared__ float s_anchor[D];
    __shared__ float s_posd[SPC];
    __shared__ u64 s_red[4];
    __shared__ u64 s_win;
    __shared__ int s_negidx[KRET];
    __shared__ float s_negd[KRET];
    __shared__ float s_dreal[2 * KRET];

    if (tid < D) s_anchor[tid] = emb[(size_t)i * D + tid];
    __syncthreads();
    const float diag_i = diag[i];
    const int li = labels1[i];
    float score[16];
#pragma unroll
    for (int it = 0; it < 16; ++it) {
        int j = it * 256 + tid;
        const float4* r = (const float4*)(emb1 + (size_t)j * D);
        float acc = 0.f;
#pragma unroll
        for (int q = 0; q < D / 4; ++q) {
            float4 vv = r[q];
            acc = fmaf(vv.x, s_anchor[4 * q + 0], acc);
            acc = fmaf(vv.y, s_anchor[4 * q + 1], acc);
            acc = fmaf(vv.z, s_anchor[4 * q + 2], acc);
            acc = fmaf(vv.w, s_anchor[4 * q + 3], acc);
        }
        float d2 = diag_i + diag[j] - 2.f * acc;
        float dist = sqrtf(fmaxf(d2, 1e-4f));
        bool is_pos = (labels[j] == li) && (j != i);
        if (is_pos) s_posd[j & (SPC - 1)] = dist;
        score[it] = dist + (is_pos ? 1e6f : 0.f);
    }
    __syncthreads();
    for (int r = 0; r < KRET; ++r) {
        u64 best = ~0ull;
#pragma unroll
        for (int it = 0; it < 16; ++it) {
            u64 p = ((u64)__float_as_uint(score[it]) << 32) | (unsigned)(it * 256 + tid);
            best = best < p ? best : p;
        }
        for (int off = 32; off > 0; off >>= 1) {
            u64 o = __shfl_down(best, off, 64);
            best = best < o ? best : o;
        }
        if ((tid & 63) == 0) s_red[tid >> 6] = best;
        __syncthreads();
        if (tid == 0) {
            u64 w2 = s_red[0];
            w2 = w2 < s_red[1] ? w2 : s_red[1];
            w2 = w2 < s_red[2] ? w2 : s_red[2];
            w2 = w2 < s_red[3] ? w2 : s_red[3];
            s_win = w2;
        }
        __syncthreads();
        u64 w2 = s_win;
        int cj = (int)(w2 & 0xffffffffu);
        if (tid == (cj & 255)) score[cj >> 8] = 1e30f;
        if (tid == 0) { s_negidx[r] = cj; s_negd[r] = __uint_as_float((unsigned)(w2 >> 32)); }
        __syncthreads();
    }
    if (tid == 0) {
        for (int a = 1; a < KRET; ++a) {
            int ix = s_negidx[a]; float dv = s_negd[a];
            int b = a - 1;
            while (b >= 0 && s_negidx[b] > ix) {
                s_negidx[b + 1] = s_negidx[b]; s_negd[b + 1] = s_negd[b]; --b;
            }
            s_negidx[b + 1] = ix; s_negd[b + 1] = dv;
        }
    }
    __syncthreads();
    {
        int wave = tid >> 6, lane = tid & 63;
        int gb = i & ~(SPC - 1);
        for (int p = wave; p < 2 * KRET; p += 4) {
            int tgt;
            if (p < KRET) {
                int k = p;
                int m = k + (k >= (i & (SPC - 1)) ? 1 : 0);
                tgt = gb + m;
            } else tgt = s_negidx[p - KRET];
            float d0 = emb[(size_t)tgt * D + lane] - s_anchor[lane];
            float d1 = emb[(size_t)tgt * D + 64 + lane] - s_anchor[64 + lane];
            float s = d0 * d0 + d1 * d1;
            for (int off = 32; off > 0; off >>= 1) s += __shfl_down(s, off, 64);
            if (lane == 0) s_dreal[p] = sqrtf(s + 1e-8f);
        }
    }
    __syncthreads();
    if (tid == 0) {
        float ls = 0.f, cnt = 0.f;
        for (int k = 0; k < KRET; ++k) {
            int m = k + (k >= (i & (SPC - 1)) ? 1 : 0);
            if (s_posd[m] < s_negd[k] + MARGIN) {
                ls += (s_dreal[k] + MARGIN) + fmaxf(MARGIN - s_dreal[KRET + k], 0.f);
                cnt += 1.f;
            }
        }
        if (ls != 0.f) atomicAdd(&ws_acc[0], ls);
        if (cnt != 0.f) atomicAdd(&ws_acc[1], cnt);
    }
}

__global__ void finalize_ws(const float* __restrict__ ws_acc, float* __restrict__ out) {
    float ls = ws_acc[0], cnt = ws_acc[1];
    out[0] = cnt > 0.f ? ls / cnt : ls;
}

extern "C" void kernel_launch(void* const* d_in, const int* in_sizes, int n_in,
                              void* d_out, int out_size, void* d_ws, size_t ws_size,
                              hipStream_t stream) {
    const float* emb     = (const float*)d_in[0];
    const int*   labels  = (const int*)d_in[1];
    const float* emb1    = (const float*)d_in[2];
    const int*   labels1 = (const int*)d_in[3];
    float* ws = (float*)d_ws;

    const size_t need = (size_t)2433024 * sizeof(float);
    if (ws_size >= need) {
        float*  diag   = ws + 4096;
        float*  posd   = ws + 8192;
        ushort* embF   = (ushort*)(ws + 65536);
        ushort* emb1F  = (ushort*)(ws + 327680);
        u32*    cand   = (u32*)(ws + 589824);
        float*  rowls  = ws + 2424832;
        float*  rowcnt = ws + 2428928;

        prep_kernel<<<NROWS / 32, 256, 0, stream>>>(emb, emb1, embF, emb1F, diag);
        dim3 grid(NROWS / 128, NROWS / 64);    // (32, 64) = 2048 blocks
        dist_mfma<<<grid, 256, 0, stream>>>(embF, emb1F, labels, labels1, diag, posd, cand);
        merge_kernel<<<NROWS / 4, 256, 0, stream>>>(emb, posd, cand, rowls, rowcnt);
        finalize_kernel<<<1, 256, 0, stream>>>(rowls, rowcnt, (float*)d_out);
    } else {
        hipMemsetAsync(d_ws, 0, 2 * sizeof(float), stream);
        float* diag = ws + 2;
        diag_kernel<<<NROWS / 4, 256, 0, stream>>>(emb, emb1, diag);
        main_kernel<<<NROWS, 256, 0, stream>>>(emb, emb1, labels, labels1, diag, ws);
        finalize_ws<<<1, 1, 0, stream>>>(ws, (float*)d_out);
    }
}

// Round 16
// 38.550 us; speedup vs baseline: 1.0847x; 1.0847x over previous
//
#include <hip/hip_runtime.h>
#include <math.h>

#define NROWS 4096
#define D 128
#define SPC 8
#define KRET 7
#define MARGIN 0.2f
#define NTILE 32              // 4096/128 column tiles (one per block-col)
#define CPR (NTILE * KRET)    // 224 candidates per row (7 per block)

typedef unsigned long long u64;
typedef unsigned int u32;
typedef __attribute__((ext_vector_type(8))) short short8;    // 8 bf16 (4 VGPRs)
typedef __attribute__((ext_vector_type(16))) float f32x16;   // 32x32 MFMA accumulator

__device__ __forceinline__ u32 minu32(u32 a, u32 b) { return a < b ? a : b; }
__device__ __forceinline__ u32 maxu32(u32 a, u32 b) { return a > b ? a : b; }

// bf16 round-to-nearest-even
__device__ __forceinline__ ushort f2bf_rne(float x) {
    unsigned u = __float_as_uint(x);
    return (ushort)((u + 0x7fffu + ((u >> 16) & 1u)) >> 16);
}
__device__ __forceinline__ u32 pack2bf(float lo, float hi) {
    return (u32)f2bf_rne(lo) | ((u32)f2bf_rne(hi) << 16);
}

// guarded sorted-7 single insert (14 ops)
__device__ __forceinline__ void ins7(u32 (&s)[KRET], u32 pk) {
#pragma unroll
    for (int k = 0; k < KRET; ++k) {
        const u32 lo = minu32(s[k], pk);
        pk = maxu32(s[k], pk);
        s[k] = lo;
    }
}

// dual insert of sorted pair (q0<=q1) into sorted-7 (r8/r12-validated; uses old s)
__device__ __forceinline__ void ins7x2(u32 (&s)[KRET], u32 q0, u32 q1) {
    s[6] = minu32(s[6], minu32(maxu32(s[5], q0), maxu32(s[4], q1)));
    s[5] = minu32(s[5], minu32(maxu32(s[4], q0), maxu32(s[3], q1)));
    s[4] = minu32(s[4], minu32(maxu32(s[3], q0), maxu32(s[2], q1)));
    s[3] = minu32(s[3], minu32(maxu32(s[2], q0), maxu32(s[1], q1)));
    s[2] = minu32(s[2], minu32(maxu32(s[1], q0), maxu32(s[0], q1)));
    s[1] = minu32(s[1], minu32(maxu32(s[0], q0), q1));
    s[0] = minu32(s[0], q0);
}

// Fragment-order bf16 layout (both matrices):
//   chunk(g, kkg, hi) = ((g*8 + kkg)*2 + hi) * 256 u16  (512 B); lane slot il*8 u16.
// -> wave frag read is a contiguous 1024 B global load (coalesced, L2-hot).
//
// ws layout (floats) — non-overlapping:
//   [4096 .. 8191]        diag
//   [8192 .. 40959]       posd (4096 x 8 f32, clamped d^2)
//   [65536 .. 327679]     embF  (fragment-order bf16, 1 MB)
//   [327680 .. 589823]    emb1F (fragment-order bf16, 1 MB)
//   [589824 .. 1507327]   cand (u32, 4096 x 224)
//   [1507328 .. 1511423]  rowls
//   [1511424 .. 1515519]  rowcnt
// Fallback path: [0],[1] accum, [2..2+NROWS) diag.

// ---- prep: f32 -> fragment-order bf16 + exact f32 Gram diagonal ----
__global__ __launch_bounds__(256) void prep_kernel(const float* __restrict__ emb,
                                                   const float* __restrict__ emb1,
                                                   ushort* __restrict__ embF,
                                                   ushort* __restrict__ emb1F,
                                                   float* __restrict__ diag) {
    __shared__ float pls[4][32];
    const int t = threadIdx.x;
    const int wv = t >> 6, l = t & 63;
    const int il = l & 31, hi = l >> 5;
    const int g = blockIdx.x;            // row-group 0..127
    const int row = g * 32 + il;
    const float* pa = emb  + (size_t)row * D;
    const float* pb = emb1 + (size_t)row * D;
    float dacc = 0.f;
#pragma unroll
    for (int kp = 0; kp < 2; ++kp) {
        const int kkg = wv * 2 + kp;
        const int k0 = kkg * 16 + hi * 8;
        const float4 a0 = *(const float4*)(pa + k0);
        const float4 a1 = *(const float4*)(pa + k0 + 4);
        const float4 b0 = *(const float4*)(pb + k0);
        const float4 b1 = *(const float4*)(pb + k0 + 4);
        dacc += a0.x * b0.x + a0.y * b0.y + a0.z * b0.z + a0.w * b0.w;
        dacc += a1.x * b1.x + a1.y * b1.y + a1.z * b1.z + a1.w * b1.w;
        uint4 ua, ub;
        ua.x = pack2bf(a0.x, a0.y); ua.y = pack2bf(a0.z, a0.w);
        ua.z = pack2bf(a1.x, a1.y); ua.w = pack2bf(a1.z, a1.w);
        ub.x = pack2bf(b0.x, b0.y); ub.y = pack2bf(b0.z, b0.w);
        ub.z = pack2bf(b1.x, b1.y); ub.w = pack2bf(b1.z, b1.w);
        const size_t dst = ((size_t)(g * 8 + kkg) * 2 + hi) * 256 + il * 8;  // u16 units
        *(uint4*)(embF + dst)  = ua;
        *(uint4*)(emb1F + dst) = ub;
    }
    dacc += __shfl_xor(dacc, 32, 64);    // combine k-halves (hi 0/1)
    if (hi == 0) pls[wv][il] = dacc;
    __syncthreads();
    if (t < 32) diag[g * 32 + t] = (pls[0][t] + pls[1][t]) + (pls[2][t] + pls[3][t]);
}

// ---- dist: 128x128 tile, swapped-operand 32x32x16 MFMA, tile-interleaved schedule ----
// r14 structure; selection now uses TWO independent sorted-7 lists (sA, sB) so the
// serial guard->insert dependency splits into two interleavable chains. Union of the
// two lists contains the top-7; exact u32 (score,col) lex tie-break preserved.
__global__ __launch_bounds__(256, 4) void dist_mfma(const ushort* __restrict__ embF,
                                                    const ushort* __restrict__ emb1F,
                                                    const int* __restrict__ labels,
                                                    const int* __restrict__ labels1,
                                                    const float* __restrict__ diag,
                                                    float* __restrict__ posd, u32* __restrict__ cand) {
    __shared__ float sdA[128], sdB[128];
    __shared__ int sLi[128], sLj[128];
    __shared__ int s_lmin[4], s_lmax[4];

    const int t = threadIdx.x;
    const int i0 = blockIdx.y * 128, j0 = blockIdx.x * 128;
    const int w = t >> 6, l = t & 63;

    {   // diag + labels -> LDS, plus per-wave label min/max for block-uniform pos gating
        int lab;
        if (t < 128) { sdA[t] = diag[i0 + t]; lab = labels1[i0 + t]; sLi[t] = lab; }
        else         { sdB[t - 128] = diag[j0 + t - 128]; lab = labels[j0 + t - 128]; sLj[t - 128] = lab; }
        int mn = lab, mx = lab;
#pragma unroll
        for (int off = 1; off < 64; off <<= 1) {
            mn = min(mn, __shfl_xor(mn, off, 64));
            mx = max(mx, __shfl_xor(mx, off, 64));
        }
        if (l == 0) { s_lmin[w] = mn; s_lmax[w] = mx; }
    }

    const int il = l & 31;            // lane's i within wave (C/D col)
    const int hi = l >> 5;            // j-half select (C/D row +4*hi)
    const int irow = w * 32 + il;     // block-local anchor row
    const int laneoff = hi * 256 + il * 8;   // u16: contiguous 1024B per wave instr
    const ushort* Ab = embF  + ((size_t)(blockIdx.y * 4 + w) * 8) * 512 + laneoff;
    const ushort* Bb = emb1F + ((size_t)(blockIdx.x * 4) * 8) * 512 + laneoff;

    // cache the anchor-row frags (loads issue before the barrier)
    short8 bfr[8];
#pragma unroll
    for (int kkg = 0; kkg < 8; ++kkg)
        bfr[kkg] = *(const short8*)(Ab + (size_t)kkg * 512);

    __syncthreads();          // the ONLY barrier

    const bool hasPos = !((max(s_lmax[0], s_lmax[1]) < min(s_lmin[2], s_lmin[3])) ||
                          (max(s_lmax[2], s_lmax[3]) < min(s_lmin[0], s_lmin[1])));
    const float di = sdA[irow];
    const int gi = i0 + irow;
    const int li = hasPos ? sLi[irow] : 0;

    u32 sA[KRET], sB[KRET];
#pragma unroll
    for (int k = 0; k < KRET; ++k) { sA[k] = 0xFFFFFFFFu; sB[k] = 0xFFFFFFFFu; }

#pragma unroll
    for (int n = 0; n < 4; ++n) {
        f32x16 acc;
#pragma unroll
        for (int r = 0; r < 16; ++r) acc[r] = 0.f;
#pragma unroll
        for (int kkg = 0; kkg < 8; ++kkg) {
            const short8 afr = *(const short8*)(Bb + (size_t)(n * 8 + kkg) * 512);
            acc = __builtin_amdgcn_mfma_f32_32x32x16_bf16(afr, bfr[kkg], acc, 0, 0, 0);
        }

        // epilogue tile n: j_local = 32n + 8g + 4*hi + q  (g = reg>>2, q = reg&3)
#pragma unroll
        for (int g = 0; g < 4; ++g) {
            const int jb = n * 32 + 8 * g + 4 * hi;
            const float4 dj4 = *(const float4*)(sdB + jb);
            const float djv[4] = {dj4.x, dj4.y, dj4.z, dj4.w};
            u32 pk[4];
            if (!hasPos) {
#pragma unroll
                for (int q = 0; q < 4; ++q) {
                    const int r = g * 4 + q;
                    const float d2c = fmaxf(fmaf(-2.f, acc[r], di + djv[q]), 1e-4f);
                    pk[q] = (__float_as_uint(d2c) & 0xFFFF0000u) | (u32)(j0 + jb + q);
                }
            } else {
                const int4 lj4 = *(const int4*)(sLj + jb);
                const int ljv[4] = {lj4.x, lj4.y, lj4.z, lj4.w};
#pragma unroll
                for (int q = 0; q < 4; ++q) {
                    const int r = g * 4 + q;
                    const int gj = j0 + jb + q;
                    const float d2c = fmaxf(fmaf(-2.f, acc[r], di + djv[q]), 1e-4f);
                    const bool pos = (ljv[q] == li) && (gi != gj);
                    if (pos) posd[(size_t)gi * SPC + (gj & (SPC - 1))] = d2c;
                    pk[q] = (pos ? 0xFFFF0000u : (__float_as_uint(d2c) & 0xFFFF0000u)) | (u32)gj;
                }
            }
            // pair 0 -> chain A, pair 1 -> chain B (independent serial chains)
            {
                const u32 q0 = minu32(pk[0], pk[1]), q1 = maxu32(pk[0], pk[1]);
                if (q0 < sA[KRET - 1]) ins7x2(sA, q0, q1);
            }
            {
                const u32 q0 = minu32(pk[2], pk[3]), q1 = maxu32(pk[2], pk[3]);
                if (q0 < sB[KRET - 1]) ins7x2(sB, q0, q1);
            }
        }
    }

    // merge chain B into chain A (7 guarded inserts; sB ascending so guard is exact)
#pragma unroll
    for (int k = 0; k < KRET; ++k) if (sB[k] < sA[KRET - 1]) ins7(sA, sB[k]);

    // merge the two lane-halves of each row (exchange originals first, then insert)
    u32 o[KRET];
#pragma unroll
    for (int k = 0; k < KRET; ++k) o[k] = (u32)__shfl_xor((int)sA[k], 32, 64);
#pragma unroll
    for (int k = 0; k < KRET; ++k) if (o[k] < sA[KRET - 1]) ins7(sA, o[k]);

    if (hi == 0) {
        u32* cw = cand + (size_t)gi * CPR + (j0 >> 7) * KRET;
#pragma unroll
        for (int k = 0; k < KRET; ++k) cw[k] = sA[k];
    }
}

// ---- merge 224 u32 candidates/row -> global top-7, validity, loss. Wave per row. ----
__global__ __launch_bounds__(256) void merge_kernel(const float* __restrict__ emb,
                                                    const float* __restrict__ posd,
                                                    const u32* __restrict__ cand,
                                                    float* __restrict__ rowls,
                                                    float* __restrict__ rowcnt) {
    const int lane = threadIdx.x & 63;
    const int i = blockIdx.x * 4 + (threadIdx.x >> 6);
    const u32* cr = cand + (size_t)i * CPR;
    u32 e[4];
    e[0] = cr[lane];
    e[1] = cr[64 + lane];
    e[2] = cr[128 + lane];
    e[3] = (lane < CPR - 192) ? cr[192 + lane] : 0xFFFFFFFFu;

    u32 w[KRET];
#pragma unroll
    for (int r = 0; r < KRET; ++r) {
        u32 m = minu32(minu32(e[0], e[1]), minu32(e[2], e[3]));
#pragma unroll
        for (int off = 1; off < 64; off <<= 1) m = minu32(m, (u32)__shfl_xor((int)m, off, 64));
        w[r] = m;
#pragma unroll
        for (int q = 0; q < 4; ++q) e[q] = (e[q] == m) ? 0xFFFFFFFFu : e[q];
    }

    // sort winners by column index: rotate to (col12 << 20 | score16 << 4), Batcher-8
    u32 s[8];
#pragma unroll
    for (int r = 0; r < KRET; ++r) s[r] = (w[r] << 20) | (w[r] >> 12);
    s[7] = 0xFFFFFFFFu;
#define CE(x, y) { u32 lo = minu32(s[x], s[y]); u32 hi2 = maxu32(s[x], s[y]); s[x] = lo; s[y] = hi2; }
    CE(0,1) CE(2,3) CE(4,5) CE(6,7)
    CE(0,2) CE(1,3) CE(4,6) CE(5,7)
    CE(1,2) CE(5,6)
    CE(0,4) CE(1,5) CE(2,6) CE(3,7)
    CE(2,4) CE(3,5)
    CE(1,2) CE(3,4) CE(5,6)
#undef CE

    const int ig = i & (SPC - 1);
    float ls = 0.f, cnt = 0.f;
    bool any = false;
    bool v[KRET];
    int nidx[KRET];
#pragma unroll
    for (int k = 0; k < KRET; ++k) {
        nidx[k] = (int)(s[k] >> 20);
        const float d2n = __uint_as_float(((s[k] >> 4) & 0xFFFF0u) << 12);  // score16 << 16
        const float dneg = sqrtf(d2n);
        const int m = k + (k >= ig ? 1 : 0);
        const float dp = sqrtf(posd[(size_t)i * SPC + m]);
        v[k] = dp < dneg + MARGIN;       // wave-uniform
        any = any || v[k];
    }

    if (any) {
        const float a0 = emb[(size_t)i * D + lane];
        const float a1 = emb[(size_t)i * D + 64 + lane];
#pragma unroll
        for (int k = 0; k < KRET; ++k) {
            if (v[k]) {
                const int m = k + (k >= ig ? 1 : 0);
                const int tp = (i & ~(SPC - 1)) + m;
                const int tn = nidx[k];
                float d0 = emb[(size_t)tp * D + lane] - a0;
                float d1 = emb[(size_t)tp * D + 64 + lane] - a1;
                float sp = d0 * d0 + d1 * d1;
                float g0 = emb[(size_t)tn * D + lane] - a0;
                float g1 = emb[(size_t)tn * D + 64 + lane] - a1;
                float sn = g0 * g0 + g1 * g1;
#pragma unroll
                for (int off = 1; off < 64; off <<= 1) {
                    sp += __shfl_xor(sp, off, 64);
                    sn += __shfl_xor(sn, off, 64);
                }
                ls += (sqrtf(sp + 1e-8f) + MARGIN) + fmaxf(MARGIN - sqrtf(sn + 1e-8f), 0.f);
                cnt += 1.f;
            }
        }
    }
    if (lane == 0) {           // always write: poison-safe, deterministic
        rowls[i] = ls;
        rowcnt[i] = cnt;
    }
}

// ---- deterministic single-block reduction over 4096 per-row partials ----
__global__ __launch_bounds__(256) void finalize_kernel(const float* __restrict__ rowls,
                                                       const float* __restrict__ rowcnt,
                                                       float* __restrict__ out) {
    const int t = threadIdx.x;
    __shared__ float sls[4], scnt[4];
    float ls = 0.f, cnt = 0.f;
#pragma unroll
    for (int q = 0; q < NROWS / 256; ++q) {
        ls += rowls[q * 256 + t];
        cnt += rowcnt[q * 256 + t];
    }
#pragma unroll
    for (int off = 1; off < 64; off <<= 1) {
        ls += __shfl_xor(ls, off, 64);
        cnt += __shfl_xor(cnt, off, 64);
    }
    if ((t & 63) == 0) { sls[t >> 6] = ls; scnt[t >> 6] = cnt; }
    __syncthreads();
    if (t == 0) {
        float L = sls[0] + sls[1] + sls[2] + sls[3];
        float C = scnt[0] + scnt[1] + scnt[2] + scnt[3];
        out[0] = C > 0.f ? L / C : L;
    }
}

// ---------------- Fallback path (round-1, only if ws too small) ----------------
__global__ __launch_bounds__(256) void diag_kernel(const float* __restrict__ emb,
                                                   const float* __restrict__ emb1,
                                                   float* __restrict__ diag) {
    int wave = threadIdx.x >> 6;
    int lane = threadIdx.x & 63;
    int row = blockIdx.x * 4 + wave;
    const float* a = emb + (size_t)row * D;
    const float* b = emb1 + (size_t)row * D;
    float s = a[lane] * b[lane] + a[lane + 64] * b[lane + 64];
    for (int off = 32; off > 0; off >>= 1) s += __shfl_down(s, off, 64);
    if (lane == 0) diag[row] = s;
}

__global__ __launch_bounds__(256) void main_kernel(const float* __restrict__ emb,
                                                   const float* __restrict__ emb1,
                                                   const int* __restrict__ labels,
                                                   const int* __restrict__ labels1,
                                                   const float* __restrict__ diag,
                                                   float* __restrict__ ws_acc) {
    const int i = blockIdx.x;
    const int tid = threadIdx.x;
    __shared__ float s_anchor[D];
    __shared__ float s_posd[SPC];
    __shared__ u64 s_red[4];
    __shared__ u64 s_win;
    __shared__ int s_negidx[KRET];
    __shared__ float s_negd[KRET];
    __shared__ float s_dreal[2 * KRET];

    if (tid < D) s_anchor[tid] = emb[(size_t)i * D + tid];
    __syncthreads();
    const float diag_i = diag[i];
    const int li = labels1[i];
    float score[16];
#pragma unroll
    for (int it = 0; it < 16; ++it) {
        int j = it * 256 + tid;
        const float4* r = (const float4*)(emb1 + (size_t)j * D);
        float acc = 0.f;
#pragma unroll
        for (int q = 0; q < D / 4; ++q) {
            float4 vv = r[q];
            acc = fmaf(vv.x, s_anchor[4 * q + 0], acc);
            acc = fmaf(vv.y, s_anchor[4 * q + 1], acc);
            acc = fmaf(vv.z, s_anchor[4 * q + 2], acc);
            acc = fmaf(vv.w, s_anchor[4 * q + 3], acc);
        }
        float d2 = diag_i + diag[j] - 2.f * acc;
        float dist = sqrtf(fmaxf(d2, 1e-4f));
        bool is_pos = (labels[j] == li) && (j != i);
        if (is_pos) s_posd[j & (SPC - 1)] = dist;
        score[it] = dist + (is_pos ? 1e6f : 0.f);
    }
    __syncthreads();
    for (int r = 0; r < KRET; ++r) {
        u64 best = ~0ull;
#pragma unroll
        for (int it = 0; it < 16; ++it) {
            u64 p = ((u64)__float_as_uint(score[it]) << 32) | (unsigned)(it * 256 + tid);
            best = best < p ? best : p;
        }
        for (int off = 32; off > 0; off >>= 1) {
            u64 o = __shfl_down(best, off, 64);
            best = best < o ? best : o;
        }
        if ((tid & 63) == 0) s_red[tid >> 6] = best;
        __syncthreads();
        if (tid == 0) {
            u64 w2 = s_red[0];
            w2 = w2 < s_red[1] ? w2 : s_red[1];
            w2 = w2 < s_red[2] ? w2 : s_red[2];
            w2 = w2 < s_red[3] ? w2 : s_red[3];
            s_win = w2;
        }
        __syncthreads();
        u64 w2 = s_win;
        int cj = (int)(w2 & 0xffffffffu);
        if (tid == (cj & 255)) score[cj >> 8] = 1e30f;
        if (tid == 0) { s_negidx[r] = cj; s_negd[r] = __uint_as_float((unsigned)(w2 >> 32)); }
        __syncthreads();
    }
    if (tid == 0) {
        for (int a = 1; a < KRET; ++a) {
            int ix = s_negidx[a]; float dv = s_negd[a];
            int b = a - 1;
            while (b >= 0 && s_negidx[b] > ix) {
                s_negidx[b + 1] = s_negidx[b]; s_negd[b + 1] = s_negd[b]; --b;
            }
            s_negidx[b + 1] = ix; s_negd[b + 1] = dv;
        }
    }
    __syncthreads();
    {
        int wave = tid >> 6, lane = tid & 63;
        int gb = i & ~(SPC - 1);
        for (int p = wave; p < 2 * KRET; p += 4) {
            int tgt;
            if (p < KRET) {
                int k = p;
                int m = k + (k >= (i & (SPC - 1)) ? 1 : 0);
                tgt = gb + m;
            } else tgt = s_negidx[p - KRET];
            float d0 = emb[(size_t)tgt * D + lane] - s_anchor[lane];
            float d1 = emb[(size_t)tgt * D + 64 + lane] - s_anchor[64 + lane];
            float s = d0 * d0 + d1 * d1;
            for (int off = 32; off > 0; off >>= 1) s += __shfl_down(s, off, 64);
            if (lane == 0) s_dreal[p] = sqrtf(s + 1e-8f);
        }
    }
    __syncthreads();
    if (tid == 0) {
        float ls = 0.f, cnt = 0.f;
        for (int k = 0; k < KRET; ++k) {
            int m = k + (k >= (i & (SPC - 1)) ? 1 : 0);
            if (s_posd[m] < s_negd[k] + MARGIN) {
                ls += (s_dreal[k] + MARGIN) + fmaxf(MARGIN - s_dreal[KRET + k], 0.f);
                cnt += 1.f;
            }
        }
        if (ls != 0.f) atomicAdd(&ws_acc[0], ls);
        if (cnt != 0.f) atomicAdd(&ws_acc[1], cnt);
    }
}

__global__ void finalize_ws(const float* __restrict__ ws_acc, float* __restrict__ out) {
    float ls = ws_acc[0], cnt = ws_acc[1];
    out[0] = cnt > 0.f ? ls / cnt : ls;
}

extern "C" void kernel_launch(void* const* d_in, const int* in_sizes, int n_in,
                              void* d_out, int out_size, void* d_ws, size_t ws_size,
                              hipStream_t stream) {
    const float* emb     = (const float*)d_in[0];
    const int*   labels  = (const int*)d_in[1];
    const float* emb1    = (const float*)d_in[2];
    const int*   labels1 = (const int*)d_in[3];
    float* ws = (float*)d_ws;

    const size_t need = (size_t)1515520 * sizeof(float);
    if (ws_size >= need) {
        float*  diag   = ws + 4096;
        float*  posd   = ws + 8192;
        ushort* embF   = (ushort*)(ws + 65536);
        ushort* emb1F  = (ushort*)(ws + 327680);
        u32*    cand   = (u32*)(ws + 589824);
        float*  rowls  = ws + 1507328;
        float*  rowcnt = ws + 1511424;

        prep_kernel<<<NROWS / 32, 256, 0, stream>>>(emb, emb1, embF, emb1F, diag);
        dim3 grid(NROWS / 128, NROWS / 128);
        dist_mfma<<<grid, 256, 0, stream>>>(embF, emb1F, labels, labels1, diag, posd, cand);
        merge_kernel<<<NROWS / 4, 256, 0, stream>>>(emb, posd, cand, rowls, rowcnt);
        finalize_kernel<<<1, 256, 0, stream>>>(rowls, rowcnt, (float*)d_out);
    } else {
        hipMemsetAsync(d_ws, 0, 2 * sizeof(float), stream);
        float* diag = ws + 2;
        diag_kernel<<<NROWS / 4, 256, 0, stream>>>(emb, emb1, diag);
        main_kernel<<<NROWS, 256, 0, stream>>>(emb, emb1, labels, labels1, diag, ws);
        finalize_ws<<<1, 1, 0, stream>>>(ws, (float*)d_out);
    }
}

// Round 17
// 37.340 us; speedup vs baseline: 1.1199x; 1.0324x over previous
//
#include <hip/hip_runtime.h>
#include <math.h>

#define NROWS 4096
#define D 128
#define SPC 8
#define KRET 7
#define MARGIN 0.2f
#define NTILE 32              // 4096/128 column tiles (one per block-col)
#define CPR (NTILE * KRET)    // 224 candidates per row (7 per block)

typedef unsigned long long u64;
typedef unsigned int u32;
typedef __attribute__((ext_vector_type(8))) short short8;    // 8 bf16 (4 VGPRs)
typedef __attribute__((ext_vector_type(16))) float f32x16;   // 32x32 MFMA accumulator

__device__ __forceinline__ u32 minu32(u32 a, u32 b) { return a < b ? a : b; }
__device__ __forceinline__ u32 maxu32(u32 a, u32 b) { return a > b ? a : b; }

// bf16 round-to-nearest-even
__device__ __forceinline__ ushort f2bf_rne(float x) {
    unsigned u = __float_as_uint(x);
    return (ushort)((u + 0x7fffu + ((u >> 16) & 1u)) >> 16);
}
__device__ __forceinline__ u32 pack2bf(float lo, float hi) {
    return (u32)f2bf_rne(lo) | ((u32)f2bf_rne(hi) << 16);
}

// guarded sorted-7 single insert (14 ops)
__device__ __forceinline__ void ins7(u32 (&s)[KRET], u32 pk) {
#pragma unroll
    for (int k = 0; k < KRET; ++k) {
        const u32 lo = minu32(s[k], pk);
        pk = maxu32(s[k], pk);
        s[k] = lo;
    }
}

// dual insert of sorted pair (q0<=q1) into sorted-7 (r8/r12-validated; uses old s)
__device__ __forceinline__ void ins7x2(u32 (&s)[KRET], u32 q0, u32 q1) {
    s[6] = minu32(s[6], minu32(maxu32(s[5], q0), maxu32(s[4], q1)));
    s[5] = minu32(s[5], minu32(maxu32(s[4], q0), maxu32(s[3], q1)));
    s[4] = minu32(s[4], minu32(maxu32(s[3], q0), maxu32(s[2], q1)));
    s[3] = minu32(s[3], minu32(maxu32(s[2], q0), maxu32(s[1], q1)));
    s[2] = minu32(s[2], minu32(maxu32(s[1], q0), maxu32(s[0], q1)));
    s[1] = minu32(s[1], minu32(maxu32(s[0], q0), q1));
    s[0] = minu32(s[0], q0);
}

// Fragment-order bf16 layout (both matrices):
//   chunk(g, kkg, hi) = ((g*8 + kkg)*2 + hi) * 256 u16  (512 B); lane slot il*8 u16.
// -> wave frag read is a contiguous 1024 B global load (coalesced, L2-hot).
//
// ws layout (floats) — non-overlapping:
//   [4096 .. 8191]        diag
//   [8192 .. 40959]       posd (4096 x 8 f32, clamped d^2)
//   [65536 .. 327679]     embF  (fragment-order bf16, 1 MB)
//   [327680 .. 589823]    emb1F (fragment-order bf16, 1 MB)
//   [589824 .. 1507327]   cand (u32, 4096 x 224)
//   [1507328 .. 1511423]  rowls
//   [1511424 .. 1515519]  rowcnt
// Fallback path: [0],[1] accum, [2..2+NROWS) diag.

// ---- prep: f32 -> fragment-order bf16 + exact f32 Gram diagonal ----
__global__ __launch_bounds__(256) void prep_kernel(const float* __restrict__ emb,
                                                   const float* __restrict__ emb1,
                                                   ushort* __restrict__ embF,
                                                   ushort* __restrict__ emb1F,
                                                   float* __restrict__ diag) {
    __shared__ float pls[4][32];
    const int t = threadIdx.x;
    const int wv = t >> 6, l = t & 63;
    const int il = l & 31, hi = l >> 5;
    const int g = blockIdx.x;            // row-group 0..127
    const int row = g * 32 + il;
    const float* pa = emb  + (size_t)row * D;
    const float* pb = emb1 + (size_t)row * D;
    float dacc = 0.f;
#pragma unroll
    for (int kp = 0; kp < 2; ++kp) {
        const int kkg = wv * 2 + kp;
        const int k0 = kkg * 16 + hi * 8;
        const float4 a0 = *(const float4*)(pa + k0);
        const float4 a1 = *(const float4*)(pa + k0 + 4);
        const float4 b0 = *(const float4*)(pb + k0);
        const float4 b1 = *(const float4*)(pb + k0 + 4);
        dacc += a0.x * b0.x + a0.y * b0.y + a0.z * b0.z + a0.w * b0.w;
        dacc += a1.x * b1.x + a1.y * b1.y + a1.z * b1.z + a1.w * b1.w;
        uint4 ua, ub;
        ua.x = pack2bf(a0.x, a0.y); ua.y = pack2bf(a0.z, a0.w);
        ua.z = pack2bf(a1.x, a1.y); ua.w = pack2bf(a1.z, a1.w);
        ub.x = pack2bf(b0.x, b0.y); ub.y = pack2bf(b0.z, b0.w);
        ub.z = pack2bf(b1.x, b1.y); ub.w = pack2bf(b1.z, b1.w);
        const size_t dst = ((size_t)(g * 8 + kkg) * 2 + hi) * 256 + il * 8;  // u16 units
        *(uint4*)(embF + dst)  = ua;
        *(uint4*)(emb1F + dst) = ub;
    }
    dacc += __shfl_xor(dacc, 32, 64);    // combine k-halves (hi 0/1)
    if (hi == 0) pls[wv][il] = dacc;
    __syncthreads();
    if (t < 32) diag[g * 32 + t] = (pls[0][t] + pls[1][t]) + (pls[2][t] + pls[3][t]);
}

// ---- dist: 128x128 tile, swapped-operand 32x32x16 MFMA, tile-interleaved schedule ----
// r14 structure (best measured: 37.6 us total). One tweak: tile-0's Bb frags load
// BEFORE the barrier (register-only; latency overlaps the label-staging barrier).
__global__ __launch_bounds__(256, 4) void dist_mfma(const ushort* __restrict__ embF,
                                                    const ushort* __restrict__ emb1F,
                                                    const int* __restrict__ labels,
                                                    const int* __restrict__ labels1,
                                                    const float* __restrict__ diag,
                                                    float* __restrict__ posd, u32* __restrict__ cand) {
    __shared__ float sdA[128], sdB[128];
    __shared__ int sLi[128], sLj[128];
    __shared__ int s_lmin[4], s_lmax[4];

    const int t = threadIdx.x;
    const int i0 = blockIdx.y * 128, j0 = blockIdx.x * 128;
    const int w = t >> 6, l = t & 63;

    {   // diag + labels -> LDS, plus per-wave label min/max for block-uniform pos gating
        int lab;
        if (t < 128) { sdA[t] = diag[i0 + t]; lab = labels1[i0 + t]; sLi[t] = lab; }
        else         { sdB[t - 128] = diag[j0 + t - 128]; lab = labels[j0 + t - 128]; sLj[t - 128] = lab; }
        int mn = lab, mx = lab;
#pragma unroll
        for (int off = 1; off < 64; off <<= 1) {
            mn = min(mn, __shfl_xor(mn, off, 64));
            mx = max(mx, __shfl_xor(mx, off, 64));
        }
        if (l == 0) { s_lmin[w] = mn; s_lmax[w] = mx; }
    }

    const int il = l & 31;            // lane's i within wave (C/D col)
    const int hi = l >> 5;            // j-half select (C/D row +4*hi)
    const int irow = w * 32 + il;     // block-local anchor row
    const int laneoff = hi * 256 + il * 8;   // u16: contiguous 1024B per wave instr
    const ushort* Ab = embF  + ((size_t)(blockIdx.y * 4 + w) * 8) * 512 + laneoff;
    const ushort* Bb = emb1F + ((size_t)(blockIdx.x * 4) * 8) * 512 + laneoff;

    // cache the anchor-row frags + tile-0 B frags (register-only; issue before barrier)
    short8 bfr[8];
#pragma unroll
    for (int kkg = 0; kkg < 8; ++kkg)
        bfr[kkg] = *(const short8*)(Ab + (size_t)kkg * 512);
    short8 afr0[8];
#pragma unroll
    for (int kkg = 0; kkg < 8; ++kkg)
        afr0[kkg] = *(const short8*)(Bb + (size_t)kkg * 512);

    __syncthreads();          // the ONLY barrier

    const bool hasPos = !((max(s_lmax[0], s_lmax[1]) < min(s_lmin[2], s_lmin[3])) ||
                          (max(s_lmax[2], s_lmax[3]) < min(s_lmin[0], s_lmin[1])));
    const float di = sdA[irow];
    const int gi = i0 + irow;
    const int li = hasPos ? sLi[irow] : 0;

    u32 s[KRET];
#pragma unroll
    for (int k = 0; k < KRET; ++k) s[k] = 0xFFFFFFFFu;

#pragma unroll
    for (int n = 0; n < 4; ++n) {
        f32x16 acc;
#pragma unroll
        for (int r = 0; r < 16; ++r) acc[r] = 0.f;
#pragma unroll
        for (int kkg = 0; kkg < 8; ++kkg) {
            const short8 afr = (n == 0) ? afr0[kkg]
                                        : *(const short8*)(Bb + (size_t)(n * 8 + kkg) * 512);
            acc = __builtin_amdgcn_mfma_f32_32x32x16_bf16(afr, bfr[kkg], acc, 0, 0, 0);
        }

        // epilogue tile n: j_local = 32n + 8g + 4*hi + q  (g = reg>>2, q = reg&3)
#pragma unroll
        for (int g = 0; g < 4; ++g) {
            const int jb = n * 32 + 8 * g + 4 * hi;
            const float4 dj4 = *(const float4*)(sdB + jb);
            const float djv[4] = {dj4.x, dj4.y, dj4.z, dj4.w};
            u32 pk[4];
            if (!hasPos) {
#pragma unroll
                for (int q = 0; q < 4; ++q) {
                    const int r = g * 4 + q;
                    const float d2c = fmaxf(fmaf(-2.f, acc[r], di + djv[q]), 1e-4f);
                    pk[q] = (__float_as_uint(d2c) & 0xFFFF0000u) | (u32)(j0 + jb + q);
                }
            } else {
                const int4 lj4 = *(const int4*)(sLj + jb);
                const int ljv[4] = {lj4.x, lj4.y, lj4.z, lj4.w};
#pragma unroll
                for (int q = 0; q < 4; ++q) {
                    const int r = g * 4 + q;
                    const int gj = j0 + jb + q;
                    const float d2c = fmaxf(fmaf(-2.f, acc[r], di + djv[q]), 1e-4f);
                    const bool pos = (ljv[q] == li) && (gi != gj);
                    if (pos) posd[(size_t)gi * SPC + (gj & (SPC - 1))] = d2c;
                    pk[q] = (pos ? 0xFFFF0000u : (__float_as_uint(d2c) & 0xFFFF0000u)) | (u32)gj;
                }
            }
            {
                const u32 q0 = minu32(pk[0], pk[1]), q1 = maxu32(pk[0], pk[1]);
                if (q0 < s[KRET - 1]) ins7x2(s, q0, q1);
            }
            {
                const u32 q0 = minu32(pk[2], pk[3]), q1 = maxu32(pk[2], pk[3]);
                if (q0 < s[KRET - 1]) ins7x2(s, q0, q1);
            }
        }
    }

    // merge the two lane-halves of each row (exchange originals first, then insert)
    u32 o[KRET];
#pragma unroll
    for (int k = 0; k < KRET; ++k) o[k] = (u32)__shfl_xor((int)s[k], 32, 64);
#pragma unroll
    for (int k = 0; k < KRET; ++k) if (o[k] < s[KRET - 1]) ins7(s, o[k]);

    if (hi == 0) {
        u32* cw = cand + (size_t)gi * CPR + (j0 >> 7) * KRET;
#pragma unroll
        for (int k = 0; k < KRET; ++k) cw[k] = s[k];
    }
}

// ---- merge 224 u32 candidates/row -> global top-7, validity, loss. Wave per row. ----
__global__ __launch_bounds__(256) void merge_kernel(const float* __restrict__ emb,
                                                    const float* __restrict__ posd,
                                                    const u32* __restrict__ cand,
                                                    float* __restrict__ rowls,
                                                    float* __restrict__ rowcnt) {
    const int lane = threadIdx.x & 63;
    const int i = blockIdx.x * 4 + (threadIdx.x >> 6);
    const u32* cr = cand + (size_t)i * CPR;
    u32 e[4];
    e[0] = cr[lane];
    e[1] = cr[64 + lane];
    e[2] = cr[128 + lane];
    e[3] = (lane < CPR - 192) ? cr[192 + lane] : 0xFFFFFFFFu;

    u32 w[KRET];
#pragma unroll
    for (int r = 0; r < KRET; ++r) {
        u32 m = minu32(minu32(e[0], e[1]), minu32(e[2], e[3]));
#pragma unroll
        for (int off = 1; off < 64; off <<= 1) m = minu32(m, (u32)__shfl_xor((int)m, off, 64));
        w[r] = m;
#pragma unroll
        for (int q = 0; q < 4; ++q) e[q] = (e[q] == m) ? 0xFFFFFFFFu : e[q];
    }

    // sort winners by column index: rotate to (col12 << 20 | score16 << 4), Batcher-8
    u32 s[8];
#pragma unroll
    for (int r = 0; r < KRET; ++r) s[r] = (w[r] << 20) | (w[r] >> 12);
    s[7] = 0xFFFFFFFFu;
#define CE(x, y) { u32 lo = minu32(s[x], s[y]); u32 hi2 = maxu32(s[x], s[y]); s[x] = lo; s[y] = hi2; }
    CE(0,1) CE(2,3) CE(4,5) CE(6,7)
    CE(0,2) CE(1,3) CE(4,6) CE(5,7)
    CE(1,2) CE(5,6)
    CE(0,4) CE(1,5) CE(2,6) CE(3,7)
    CE(2,4) CE(3,5)
    CE(1,2) CE(3,4) CE(5,6)
#undef CE

    const int ig = i & (SPC - 1);
    float ls = 0.f, cnt = 0.f;
    bool any = false;
    bool v[KRET];
    int nidx[KRET];
#pragma unroll
    for (int k = 0; k < KRET; ++k) {
        nidx[k] = (int)(s[k] >> 20);
        const float d2n = __uint_as_float(((s[k] >> 4) & 0xFFFF0u) << 12);  // score16 << 16
        const float dneg = sqrtf(d2n);
        const int m = k + (k >= ig ? 1 : 0);
        const float dp = sqrtf(posd[(size_t)i * SPC + m]);
        v[k] = dp < dneg + MARGIN;       // wave-uniform
        any = any || v[k];
    }

    if (any) {
        const float a0 = emb[(size_t)i * D + lane];
        const float a1 = emb[(size_t)i * D + 64 + lane];
#pragma unroll
        for (int k = 0; k < KRET; ++k) {
            if (v[k]) {
                const int m = k + (k >= ig ? 1 : 0);
                const int tp = (i & ~(SPC - 1)) + m;
                const int tn = nidx[k];
                float d0 = emb[(size_t)tp * D + lane] - a0;
                float d1 = emb[(size_t)tp * D + 64 + lane] - a1;
                float sp = d0 * d0 + d1 * d1;
                float g0 = emb[(size_t)tn * D + lane] - a0;
                float g1 = emb[(size_t)tn * D + 64 + lane] - a1;
                float sn = g0 * g0 + g1 * g1;
#pragma unroll
                for (int off = 1; off < 64; off <<= 1) {
                    sp += __shfl_xor(sp, off, 64);
                    sn += __shfl_xor(sn, off, 64);
                }
                ls += (sqrtf(sp + 1e-8f) + MARGIN) + fmaxf(MARGIN - sqrtf(sn + 1e-8f), 0.f);
                cnt += 1.f;
            }
        }
    }
    if (lane == 0) {           // always write: poison-safe, deterministic
        rowls[i] = ls;
        rowcnt[i] = cnt;
    }
}

// ---- deterministic single-block reduction over 4096 per-row partials ----
__global__ __launch_bounds__(256) void finalize_kernel(const float* __restrict__ rowls,
                                                       const float* __restrict__ rowcnt,
                                                       float* __restrict__ out) {
    const int t = threadIdx.x;
    __shared__ float sls[4], scnt[4];
    float ls = 0.f, cnt = 0.f;
#pragma unroll
    for (int q = 0; q < NROWS / 256; ++q) {
        ls += rowls[q * 256 + t];
        cnt += rowcnt[q * 256 + t];
    }
#pragma unroll
    for (int off = 1; off < 64; off <<= 1) {
        ls += __shfl_xor(ls, off, 64);
        cnt += __shfl_xor(cnt, off, 64);
    }
    if ((t & 63) == 0) { sls[t >> 6] = ls; scnt[t >> 6] = cnt; }
    __syncthreads();
    if (t == 0) {
        float L = sls[0] + sls[1] + sls[2] + sls[3];
        float C = scnt[0] + scnt[1] + scnt[2] + scnt[3];
        out[0] = C > 0.f ? L / C : L;
    }
}

// ---------------- Fallback path (round-1, only if ws too small) ----------------
__global__ __launch_bounds__(256) void diag_kernel(const float* __restrict__ emb,
                                                   const float* __restrict__ emb1,
                                                   float* __restrict__ diag) {
    int wave = threadIdx.x >> 6;
    int lane = threadIdx.x & 63;
    int row = blockIdx.x * 4 + wave;
    const float* a = emb + (size_t)row * D;
    const float* b = emb1 + (size_t)row * D;
    float s = a[lane] * b[lane] + a[lane + 64] * b[lane + 64];
    for (int off = 32; off > 0; off >>= 1) s += __shfl_down(s, off, 64);
    if (lane == 0) diag[row] = s;
}

__global__ __launch_bounds__(256) void main_kernel(const float* __restrict__ emb,
                                                   const float* __restrict__ emb1,
                                                   const int* __restrict__ labels,
                                                   const int* __restrict__ labels1,
                                                   const float* __restrict__ diag,
                                                   float* __restrict__ ws_acc) {
    const int i = blockIdx.x;
    const int tid = threadIdx.x;
    __shared__ float s_anchor[D];
    __shared__ float s_posd[SPC];
    __shared__ u64 s_red[4];
    __shared__ u64 s_win;
    __shared__ int s_negidx[KRET];
    __shared__ float s_negd[KRET];
    __shared__ float s_dreal[2 * KRET];

    if (tid < D) s_anchor[tid] = emb[(size_t)i * D + tid];
    __syncthreads();
    const float diag_i = diag[i];
    const int li = labels1[i];
    float score[16];
#pragma unroll
    for (int it = 0; it < 16; ++it) {
        int j = it * 256 + tid;
        const float4* r = (const float4*)(emb1 + (size_t)j * D);
        float acc = 0.f;
#pragma unroll
        for (int q = 0; q < D / 4; ++q) {
            float4 vv = r[q];
            acc = fmaf(vv.x, s_anchor[4 * q + 0], acc);
            acc = fmaf(vv.y, s_anchor[4 * q + 1], acc);
            acc = fmaf(vv.z, s_anchor[4 * q + 2], acc);
            acc = fmaf(vv.w, s_anchor[4 * q + 3], acc);
        }
        float d2 = diag_i + diag[j] - 2.f * acc;
        float dist = sqrtf(fmaxf(d2, 1e-4f));
        bool is_pos = (labels[j] == li) && (j != i);
        if (is_pos) s_posd[j & (SPC - 1)] = dist;
        score[it] = dist + (is_pos ? 1e6f : 0.f);
    }
    __syncthreads();
    for (int r = 0; r < KRET; ++r) {
        u64 best = ~0ull;
#pragma unroll
        for (int it = 0; it < 16; ++it) {
            u64 p = ((u64)__float_as_uint(score[it]) << 32) | (unsigned)(it * 256 + tid);
            best = best < p ? best : p;
        }
        for (int off = 32; off > 0; off >>= 1) {
            u64 o = __shfl_down(best, off, 64);
            best = best < o ? best : o;
        }
        if ((tid & 63) == 0) s_red[tid >> 6] = best;
        __syncthreads();
        if (tid == 0) {
            u64 w2 = s_red[0];
            w2 = w2 < s_red[1] ? w2 : s_red[1];
            w2 = w2 < s_red[2] ? w2 : s_red[2];
            w2 = w2 < s_red[3] ? w2 : s_red[3];
            s_win = w2;
        }
        __syncthreads();
        u64 w2 = s_win;
        int cj = (int)(w2 & 0xffffffffu);
        if (tid == (cj & 255)) score[cj >> 8] = 1e30f;
        if (tid == 0) { s_negidx[r] = cj; s_negd[r] = __uint_as_float((unsigned)(w2 >> 32)); }
        __syncthreads();
    }
    if (tid == 0) {
        for (int a = 1; a < KRET; ++a) {
            int ix = s_negidx[a]; float dv = s_negd[a];
            int b = a - 1;
            while (b >= 0 && s_negidx[b] > ix) {
                s_negidx[b + 1] = s_negidx[b]; s_negd[b + 1] = s_negd[b]; --b;
            }
            s_negidx[b + 1] = ix; s_negd[b + 1] = dv;
        }
    }
    __syncthreads();
    {
        int wave = tid >> 6, lane = tid & 63;
        int gb = i & ~(SPC - 1);
        for (int p = wave; p < 2 * KRET; p += 4) {
            int tgt;
            if (p < KRET) {
                int k = p;
                int m = k + (k >= (i & (SPC - 1)) ? 1 : 0);
                tgt = gb + m;
            } else tgt = s_negidx[p - KRET];
            float d0 = emb[(size_t)tgt * D + lane] - s_anchor[lane];
            float d1 = emb[(size_t)tgt * D + 64 + lane] - s_anchor[64 + lane];
            float s = d0 * d0 + d1 * d1;
            for (int off = 32; off > 0; off >>= 1) s += __shfl_down(s, off, 64);
            if (lane == 0) s_dreal[p] = sqrtf(s + 1e-8f);
        }
    }
    __syncthreads();
    if (tid == 0) {
        float ls = 0.f, cnt = 0.f;
        for (int k = 0; k < KRET; ++k) {
            int m = k + (k >= (i & (SPC - 1)) ? 1 : 0);
            if (s_posd[m] < s_negd[k] + MARGIN) {
                ls += (s_dreal[k] + MARGIN) + fmaxf(MARGIN - s_dreal[KRET + k], 0.f);
                cnt += 1.f;
            }
        }
        if (ls != 0.f) atomicAdd(&ws_acc[0], ls);
        if (cnt != 0.f) atomicAdd(&ws_acc[1], cnt);
    }
}

__global__ void finalize_ws(const float* __restrict__ ws_acc, float* __restrict__ out) {
    float ls = ws_acc[0], cnt = ws_acc[1];
    out[0] = cnt > 0.f ? ls / cnt : ls;
}

extern "C" void kernel_launch(void* const* d_in, const int* in_sizes, int n_in,
                              void* d_out, int out_size, void* d_ws, size_t ws_size,
                              hipStream_t stream) {
    const float* emb     = (const float*)d_in[0];
    const int*   labels  = (const int*)d_in[1];
    const float* emb1    = (const float*)d_in[2];
    const int*   labels1 = (const int*)d_in[3];
    float* ws = (float*)d_ws;

    const size_t need = (size_t)1515520 * sizeof(float);
    if (ws_size >= need) {
        float*  diag   = ws + 4096;
        float*  posd   = ws + 8192;
        ushort* embF   = (ushort*)(ws + 65536);
        ushort* emb1F  = (ushort*)(ws + 327680);
        u32*    cand   = (u32*)(ws + 589824);
        float*  rowls  = ws + 1507328;
        float*  rowcnt = ws + 1511424;

        prep_kernel<<<NROWS / 32, 256, 0, stream>>>(emb, emb1, embF, emb1F, diag);
        dim3 grid(NROWS / 128, NROWS / 128);
        dist_mfma<<<grid, 256, 0, stream>>>(embF, emb1F, labels, labels1, diag, posd, cand);
        merge_kernel<<<NROWS / 4, 256, 0, stream>>>(emb, posd, cand, rowls, rowcnt);
        finalize_kernel<<<1, 256, 0, stream>>>(rowls, rowcnt, (float*)d_out);
    } else {
        hipMemsetAsync(d_ws, 0, 2 * sizeof(float), stream);
        float* diag = ws + 2;
        diag_kernel<<<NROWS / 4, 256, 0, stream>>>(emb, emb1, diag);
        main_kernel<<<NROWS, 256, 0, stream>>>(emb, emb1, labels, labels1, diag, ws);
        finalize_ws<<<1, 1, 0, stream>>>(ws, (float*)d_out);
    }
}